// Round 1
// baseline (621.963 us; speedup 1.0000x reference)
//
#include <hip/hip_runtime.h>
#include <hip/hip_bf16.h>

#define NPTS 100000
#define DHID 512
#define EPSV 1e-5f

typedef __bf16 bf16;
typedef __attribute__((ext_vector_type(8))) __bf16 bf16x8;
typedef __attribute__((ext_vector_type(4))) __bf16 bf16x4;
typedef __attribute__((ext_vector_type(4))) float f32x4;

// ---- workspace layout (bytes, all 256-aligned) ----
#define OFF_INBF   0UL            // 100000*128*2 = 25,600,000
#define OFF_W0     25600000UL     // 512*128*2
#define OFF_W1     25731072UL     // 512*512*2
#define OFF_W2     26255360UL     // 512*512*2
#define OFF_C0     26779648UL     // 512*4
#define OFF_C1     26781696UL
#define OFF_C2     26783744UL
#define OFF_PARTS  26785792UL     // 1563*512*4
#define OFF_PARTS2 29986816UL     // 64*512*4
#define OFF_H1     30117888UL     // 100000*512*2
#define OFF_H2     132517888UL    // 100000*512*2

typedef const __attribute__((address_space(1))) unsigned int* gp_t;
typedef __attribute__((address_space(3))) unsigned int* lp_t;

__device__ __forceinline__ void async_copy16(const void* g, void* l) {
    __builtin_amdgcn_global_load_lds((gp_t)g, (lp_t)l, 16, 0, 0);
}

// ---------- prep: fp32 -> bf16 ----------
__global__ __launch_bounds__(256) void cvt_bf16_kernel(const float* __restrict__ in,
                                                       bf16* __restrict__ out, long n) {
    long stride = (long)gridDim.x * blockDim.x * 4;
    for (long base = ((long)blockIdx.x * blockDim.x + threadIdx.x) * 4; base < n; base += stride) {
        float4 v = *(const float4*)(in + base);
        bf16x4 o = { (bf16)v.x, (bf16)v.y, (bf16)v.z, (bf16)v.w };
        *(bf16x4*)(out + base) = o;
    }
}

// ---------- prep: W = bf16(A - B) ----------
__global__ __launch_bounds__(256) void wdiff_kernel(const float* __restrict__ A,
                                                    const float* __restrict__ B,
                                                    bf16* __restrict__ W, long n) {
    long stride = (long)gridDim.x * blockDim.x * 4;
    for (long base = ((long)blockIdx.x * blockDim.x + threadIdx.x) * 4; base < n; base += stride) {
        float4 a = *(const float4*)(A + base);
        float4 b = *(const float4*)(B + base);
        bf16x4 o = { (bf16)(a.x - b.x), (bf16)(a.y - b.y), (bf16)(a.z - b.z), (bf16)(a.w - b.w) };
        *(bf16x4*)(W + base) = o;
    }
}

// ---------- colsum of in_set (fp32, deterministic 2-stage) ----------
__global__ __launch_bounds__(256) void colsum_in_kernel(const float* __restrict__ in,
                                                        float* __restrict__ parts) {
    __shared__ float sh[256];
    int t = threadIdx.x, blk = blockIdx.x;
    int c = t & 127, half = t >> 7;
    long rbeg = (long)blk * 196 + half;
    long rend = (long)(blk + 1) * 196; if (rend > NPTS) rend = NPTS;
    float s = 0.f;
    for (long r = rbeg; r < rend; r += 2) s += in[r * 128 + c];
    sh[t] = s;
    __syncthreads();
    if (t < 128) parts[blk * 128 + t] = sh[t] + sh[t + 128];
}

// ---------- reduce partials -> s, then c = s @ B^T (fp32, one block) ----------
__global__ __launch_bounds__(512) void reduce_c_kernel(const float* __restrict__ parts, int nparts,
                                                       int dsum, const float* __restrict__ Bm,
                                                       float* __restrict__ cvec) {
    __shared__ float ssh[512];
    int t = threadIdx.x;
    if (t < dsum) {
        float s = 0.f;
        for (int b = 0; b < nparts; ++b) s += parts[(long)b * dsum + t];
        ssh[t] = s;
    }
    __syncthreads();
    float c = 0.f;
    const float* br = Bm + (long)t * dsum;
    for (int d = 0; d < dsum; ++d) c += ssh[d] * br[d];
    cvec[t] = c;
}

// ---------- 2nd-level partial reduce over 512-wide partials ----------
__global__ __launch_bounds__(512) void part_reduce_kernel(const float* __restrict__ parts, int nparts,
                                                          int op, float* __restrict__ out) {
    int g = blockIdx.x, t = threadIdx.x;
    int chunk = (nparts + gridDim.x - 1) / gridDim.x;
    int b0 = g * chunk, b1 = b0 + chunk; if (b1 > nparts) b1 = nparts;
    float s = 0.f;  // identity 0 is valid for max too: values are post-relu >= 0
    for (int b = b0; b < b1; ++b) {
        float v = parts[(long)b * 512 + t];
        s = (op == 0) ? (s + v) : fmaxf(s, v);
    }
    out[(long)g * 512 + t] = s;
}

// ---------- final: hmax -> out = hmax @ out_w^T + out_b ----------
__global__ __launch_bounds__(512) void final_kernel(const float* __restrict__ parts2, int np,
                                                    const float* __restrict__ ow,
                                                    const float* __restrict__ ob,
                                                    float* __restrict__ out) {
    __shared__ float hm[512];
    int t = threadIdx.x;
    float m = 0.f;
    for (int b = 0; b < np; ++b) m = fmaxf(m, parts2[(long)b * 512 + t]);
    hm[t] = m;
    __syncthreads();
    if (t < 256) {
        const float* w = ow + (long)t * 512;
        float s = 0.f;
        for (int d = 0; d < 512; ++d) s += hm[d] * w[d];
        out[t] = s + ob[t];
    }
}

// ---------- fused layer: C = X@W^T (bf16 MFMA) + c ; LN ; relu ; store bf16 ; col-red ----------
// BM=64, BN=512 (full width -> LN block-local), BK=64, 512 threads = 8 waves (2Mx4N).
// LDS XOR-swizzle: 16B slot g of row r stored at slot g^(r&7); global source pre-swizzled (G21).
template<int KD, bool STORE, int REDOP>  // REDOP 0=sum, 1=max
__global__ __launch_bounds__(512, 2)
void layer_kernel(const bf16* __restrict__ X, const bf16* __restrict__ W,
                  const float* __restrict__ cvec, const float* __restrict__ gvec,
                  const float* __restrict__ bvec, bf16* __restrict__ Hout,
                  float* __restrict__ red_out) {
    static_assert(KD % 64 == 0, "");
    __shared__ __align__(128) char smem[8192 + 65536];   // Xs[64][64] + Ws[512][64] bf16
    char* Xs = smem;
    char* Ws = smem + 8192;

    const int t = threadIdx.x;
    const int lane = t & 63;
    const int wid = t >> 6;          // 0..7
    const int wm = wid >> 2;         // 0..1  (M half)
    const int wn = wid & 3;          // 0..3  (N quarter)
    const int ln15 = lane & 15;
    const int lg = lane >> 4;        // 0..3
    const int blk = blockIdx.x;
    const long row0 = (long)blk * 64;

    // per-lane column constants (8 cols: wn*128 + fn*16 + ln15)
    const int cbase = wn * 128 + ln15;
    float cv[8], gv[8], bv[8];
#pragma unroll
    for (int fn = 0; fn < 8; ++fn) {
        int col = cbase + fn * 16;
        cv[fn] = cvec[col]; gv[fn] = gvec[col]; bv[fn] = bvec[col];
    }

    f32x4 acc[2][8];
#pragma unroll
    for (int i = 0; i < 2; ++i)
#pragma unroll
        for (int j = 0; j < 8; ++j) acc[i][j] = (f32x4){0.f, 0.f, 0.f, 0.f};

    // staging geometry: ksrc slot = (lane&7)^(lane>>3) for BOTH X and W tiles
    const int ks_off = ((lane & 7) ^ (lane >> 3)) * 8;   // element offset in 64-wide k
    const int xr = 8 * wid + (lane >> 3);                // X tile row this thread stages
    long xrow = row0 + xr; if (xrow > NPTS - 1) xrow = NPTS - 1;  // clamp; masked later
    const bf16* xsrc = X + xrow * KD + ks_off;
    char* xdst = Xs + wid * 1024 + lane * 16;

    for (int ks = 0; ks < KD / 64; ++ks) {
        const int k0 = ks * 64;
        async_copy16(xsrc + k0, xdst);
#pragma unroll
        for (int q = 0; q < 8; ++q) {
            const bf16* wsrc = W + (long)(wid * 64 + q * 8 + (lane >> 3)) * KD + k0 + ks_off;
            async_copy16(wsrc, Ws + wid * 8192 + q * 1024 + lane * 16);
        }
        asm volatile("s_waitcnt vmcnt(0)" ::: "memory");
        __syncthreads();

#pragma unroll
        for (int kk = 0; kk < 2; ++kk) {
            const int gr = kk * 4 + lg;   // 16B k-slot 0..7
            bf16x8 a[2], b[8];
#pragma unroll
            for (int fm = 0; fm < 2; ++fm) {
                int row = wm * 32 + fm * 16 + ln15;
                a[fm] = *(const bf16x8*)(Xs + row * 128 + ((gr ^ (row & 7)) * 16));
            }
#pragma unroll
            for (int fn = 0; fn < 8; ++fn) {
                int rw = wn * 128 + fn * 16 + ln15;
                b[fn] = *(const bf16x8*)(Ws + rw * 128 + ((gr ^ (rw & 7)) * 16));
            }
#pragma unroll
            for (int fm = 0; fm < 2; ++fm)
#pragma unroll
                for (int fn = 0; fn < 8; ++fn)
                    acc[fm][fn] = __builtin_amdgcn_mfma_f32_16x16x32_bf16(a[fm], b[fn], acc[fm][fn], 0, 0, 0);
        }
        __syncthreads();
    }

    // ---------------- epilogue (reuses Xs region of LDS) ----------------
    float* lnred_s = (float*)smem;            // [64][4]
    float* lnred_q = (float*)(smem + 1024);   // [64][4]
    float* lnmv    = (float*)(smem + 2048);   // [64][2]
    float* csred   = (float*)(smem + 4096);   // [2][512]

    // add the broadcast c-vector (fp32-exact common term)
#pragma unroll
    for (int fm = 0; fm < 2; ++fm)
#pragma unroll
        for (int fn = 0; fn < 8; ++fn) acc[fm][fn] += cv[fn];

    // per-row sum / sumsq over this wave's 128 cols (shfl tree within 16-lane group)
    float rs[8], rq[8];
#pragma unroll
    for (int fm = 0; fm < 2; ++fm)
#pragma unroll
        for (int j = 0; j < 4; ++j) {
            float s = 0.f, q = 0.f;
#pragma unroll
            for (int fn = 0; fn < 8; ++fn) {
                float x = acc[fm][fn][j];
                s += x; q += x * x;
            }
            rs[fm * 4 + j] = s; rq[fm * 4 + j] = q;
        }
#pragma unroll
    for (int m = 1; m < 16; m <<= 1)
#pragma unroll
        for (int i = 0; i < 8; ++i) {
            rs[i] += __shfl_xor(rs[i], m);
            rq[i] += __shfl_xor(rq[i], m);
        }
    if (ln15 == 0) {
#pragma unroll
        for (int fm = 0; fm < 2; ++fm)
#pragma unroll
            for (int j = 0; j < 4; ++j) {
                int row = wm * 32 + fm * 16 + lg * 4 + j;
                lnred_s[row * 4 + wn] = rs[fm * 4 + j];
                lnred_q[row * 4 + wn] = rq[fm * 4 + j];
            }
    }
    __syncthreads();
    if (t < 64) {
        float s = lnred_s[t * 4] + lnred_s[t * 4 + 1] + lnred_s[t * 4 + 2] + lnred_s[t * 4 + 3];
        float q = lnred_q[t * 4] + lnred_q[t * 4 + 1] + lnred_q[t * 4 + 2] + lnred_q[t * 4 + 3];
        float mu = s * (1.0f / 512.0f);
        float var = q * (1.0f / 512.0f) - mu * mu;
        lnmv[t * 2] = mu;
        lnmv[t * 2 + 1] = rsqrtf(var + EPSV);
    }
    __syncthreads();

    // normalize + relu + (store bf16) ; invalid rows forced to 0 so col-reductions are masked
#pragma unroll
    for (int fm = 0; fm < 2; ++fm)
#pragma unroll
        for (int j = 0; j < 4; ++j) {
            int rloc = wm * 32 + fm * 16 + lg * 4 + j;
            long rglob = row0 + rloc;
            bool ok = rglob < NPTS;
            float mu = lnmv[rloc * 2], rstd = lnmv[rloc * 2 + 1];
#pragma unroll
            for (int fn = 0; fn < 8; ++fn) {
                float y = fmaxf((acc[fm][fn][j] - mu) * rstd * gv[fn] + bv[fn], 0.0f);
                acc[fm][fn][j] = ok ? y : 0.0f;
            }
            if (STORE && ok) {
#pragma unroll
                for (int fn = 0; fn < 8; ++fn)
                    Hout[rglob * DHID + cbase + fn * 16] = (bf16)acc[fm][fn][j];
            }
        }

    // column partials over the block's 64 rows (sum or max)
    float cp[8];
#pragma unroll
    for (int fn = 0; fn < 8; ++fn) {
        float p = 0.f;
#pragma unroll
        for (int fm = 0; fm < 2; ++fm)
#pragma unroll
            for (int j = 0; j < 4; ++j) {
                float v = acc[fm][fn][j];
                p = (REDOP == 0) ? (p + v) : fmaxf(p, v);
            }
        cp[fn] = p;
    }
#pragma unroll
    for (int m = 16; m < 64; m <<= 1)
#pragma unroll
        for (int fn = 0; fn < 8; ++fn) {
            float o = __shfl_xor(cp[fn], m);
            cp[fn] = (REDOP == 0) ? (cp[fn] + o) : fmaxf(cp[fn], o);
        }
    if (lg == 0) {
#pragma unroll
        for (int fn = 0; fn < 8; ++fn)
            csred[wm * 512 + wn * 128 + fn * 16 + ln15] = cp[fn];
    }
    __syncthreads();
    {
        float a0 = csred[t], a1 = csred[512 + t];
        red_out[(long)blk * 512 + t] = (REDOP == 0) ? (a0 + a1) : fmaxf(a0, a1);
    }
}

extern "C" void kernel_launch(void* const* d_in, const int* in_sizes, int n_in,
                              void* d_out, int out_size, void* d_ws, size_t ws_size,
                              hipStream_t stream) {
    const float* in_set = (const float*)d_in[0];
    const float* A0 = (const float*)d_in[1];
    const float* B0 = (const float*)d_in[2];
    const float* A1 = (const float*)d_in[3];
    const float* B1 = (const float*)d_in[4];
    const float* A2 = (const float*)d_in[5];
    const float* B2 = (const float*)d_in[6];
    const float* ga = (const float*)d_in[7];
    const float* be = (const float*)d_in[8];
    const float* ow = (const float*)d_in[9];
    const float* ob = (const float*)d_in[10];
    float* outp = (float*)d_out;
    char* ws = (char*)d_ws;

    bf16* in_bf = (bf16*)(ws + OFF_INBF);
    bf16* W0 = (bf16*)(ws + OFF_W0);
    bf16* W1 = (bf16*)(ws + OFF_W1);
    bf16* W2 = (bf16*)(ws + OFF_W2);
    float* c0 = (float*)(ws + OFF_C0);
    float* c1 = (float*)(ws + OFF_C1);
    float* c2 = (float*)(ws + OFF_C2);
    float* parts = (float*)(ws + OFF_PARTS);
    float* parts2 = (float*)(ws + OFF_PARTS2);
    bf16* h1 = (bf16*)(ws + OFF_H1);
    bf16* h2 = (bf16*)(ws + OFF_H2);

    const int nblk = (NPTS + 63) / 64;  // 1563

    cvt_bf16_kernel<<<2048, 256, 0, stream>>>(in_set, in_bf, (long)NPTS * 128);
    wdiff_kernel<<<64, 256, 0, stream>>>(A0, B0, W0, 512L * 128);
    wdiff_kernel<<<256, 256, 0, stream>>>(A1, B1, W1, 512L * 512);
    wdiff_kernel<<<256, 256, 0, stream>>>(A2, B2, W2, 512L * 512);

    // c0 = colsum(in_set) @ B0^T   (all fp32 — the numerically critical path)
    colsum_in_kernel<<<512, 256, 0, stream>>>(in_set, parts);
    reduce_c_kernel<<<1, 512, 0, stream>>>(parts, 512, 128, B0, c0);

    layer_kernel<128, true, 0><<<nblk, 512, 0, stream>>>(in_bf, W0, c0, ga, be, h1, parts);
    part_reduce_kernel<<<64, 512, 0, stream>>>(parts, nblk, 0, parts2);
    reduce_c_kernel<<<1, 512, 0, stream>>>(parts2, 64, 512, B1, c1);

    layer_kernel<512, true, 0><<<nblk, 512, 0, stream>>>(h1, W1, c1, ga, be, h2, parts);
    part_reduce_kernel<<<64, 512, 0, stream>>>(parts, nblk, 0, parts2);
    reduce_c_kernel<<<1, 512, 0, stream>>>(parts2, 64, 512, B2, c2);

    // layer 2: no h3 store; fused column-max partials
    layer_kernel<512, false, 1><<<nblk, 512, 0, stream>>>(h2, W2, c2, ga, be, nullptr, parts);
    part_reduce_kernel<<<64, 512, 0, stream>>>(parts, nblk, 1, parts2);
    final_kernel<<<1, 512, 0, stream>>>(parts2, 64, ow, ob, outp);
}

// Round 2
// 611.718 us; speedup vs baseline: 1.0167x; 1.0167x over previous
//
#include <hip/hip_runtime.h>
#include <hip/hip_bf16.h>

#define NPTS 100000
#define DHID 512
#define EPSV 1e-5f

typedef __bf16 bf16;
typedef __attribute__((ext_vector_type(8))) __bf16 bf16x8;
typedef __attribute__((ext_vector_type(4))) __bf16 bf16x4;
typedef __attribute__((ext_vector_type(4))) float f32x4;

// ---- workspace layout (bytes, all 256-aligned) ----
#define OFF_INBF   0UL            // 100000*128*2 = 25,600,000
#define OFF_W0     25600000UL     // 512*128*2
#define OFF_W1     25731072UL     // 512*512*2
#define OFF_W2     26255360UL     // 512*512*2
#define OFF_C0     26779648UL     // 512*4
#define OFF_C1     26781696UL
#define OFF_C2     26783744UL
#define OFF_PARTS  26785792UL     // (up to 1563)*512*4
#define OFF_PARTS2 29986816UL     // 64*512*4
#define OFF_H1     30117888UL     // 100000*512*2
#define OFF_H2     132517888UL    // 100000*512*2

typedef const __attribute__((address_space(1))) unsigned int* gp_t;
typedef __attribute__((address_space(3))) unsigned int* lp_t;

__device__ __forceinline__ void async_copy16(const void* g, void* l) {
    __builtin_amdgcn_global_load_lds((gp_t)g, (lp_t)l, 16, 0, 0);
}

// ---------- prep: fp32 -> bf16 ----------
__global__ __launch_bounds__(256) void cvt_bf16_kernel(const float* __restrict__ in,
                                                       bf16* __restrict__ out, long n) {
    long stride = (long)gridDim.x * blockDim.x * 4;
    for (long base = ((long)blockIdx.x * blockDim.x + threadIdx.x) * 4; base < n; base += stride) {
        float4 v = *(const float4*)(in + base);
        bf16x4 o = { (bf16)v.x, (bf16)v.y, (bf16)v.z, (bf16)v.w };
        *(bf16x4*)(out + base) = o;
    }
}

// ---------- prep: W = bf16(A - B) ----------
__global__ __launch_bounds__(256) void wdiff_kernel(const float* __restrict__ A,
                                                    const float* __restrict__ B,
                                                    bf16* __restrict__ W, long n) {
    long stride = (long)gridDim.x * blockDim.x * 4;
    for (long base = ((long)blockIdx.x * blockDim.x + threadIdx.x) * 4; base < n; base += stride) {
        float4 a = *(const float4*)(A + base);
        float4 b = *(const float4*)(B + base);
        bf16x4 o = { (bf16)(a.x - b.x), (bf16)(a.y - b.y), (bf16)(a.z - b.z), (bf16)(a.w - b.w) };
        *(bf16x4*)(W + base) = o;
    }
}

// ---------- colsum of in_set (fp32, deterministic 2-stage) ----------
__global__ __launch_bounds__(256) void colsum_in_kernel(const float* __restrict__ in,
                                                        float* __restrict__ parts) {
    __shared__ float sh[256];
    int t = threadIdx.x, blk = blockIdx.x;
    int c = t & 127, half = t >> 7;
    long rbeg = (long)blk * 196 + half;
    long rend = (long)(blk + 1) * 196; if (rend > NPTS) rend = NPTS;
    float s = 0.f;
    for (long r = rbeg; r < rend; r += 2) s += in[r * 128 + c];
    sh[t] = s;
    __syncthreads();
    if (t < 128) parts[blk * 128 + t] = sh[t] + sh[t + 128];
}

// ---------- reduce partials -> s, then c = s @ B^T (fp32, one block) ----------
__global__ __launch_bounds__(512) void reduce_c_kernel(const float* __restrict__ parts, int nparts,
                                                       int dsum, const float* __restrict__ Bm,
                                                       float* __restrict__ cvec) {
    __shared__ float ssh[512];
    int t = threadIdx.x;
    if (t < dsum) {
        float s = 0.f;
        for (int b = 0; b < nparts; ++b) s += parts[(long)b * dsum + t];
        ssh[t] = s;
    }
    __syncthreads();
    float c = 0.f;
    const float* br = Bm + (long)t * dsum;
    for (int d = 0; d < dsum; ++d) c += ssh[d] * br[d];
    cvec[t] = c;
}

// ---------- 2nd-level partial reduce over 512-wide partials ----------
__global__ __launch_bounds__(512) void part_reduce_kernel(const float* __restrict__ parts, int nparts,
                                                          int op, float* __restrict__ out) {
    int g = blockIdx.x, t = threadIdx.x;
    int chunk = (nparts + gridDim.x - 1) / gridDim.x;
    int b0 = g * chunk, b1 = b0 + chunk; if (b1 > nparts) b1 = nparts;
    float s = 0.f;  // identity 0 is valid for max too: values are post-relu >= 0
    for (int b = b0; b < b1; ++b) {
        float v = parts[(long)b * 512 + t];
        s = (op == 0) ? (s + v) : fmaxf(s, v);
    }
    out[(long)g * 512 + t] = s;
}

// ---------- final: hmax -> out = hmax @ out_w^T + out_b ----------
__global__ __launch_bounds__(512) void final_kernel(const float* __restrict__ parts2, int np,
                                                    const float* __restrict__ ow,
                                                    const float* __restrict__ ob,
                                                    float* __restrict__ out) {
    __shared__ float hm[512];
    int t = threadIdx.x;
    float m = 0.f;
    for (int b = 0; b < np; ++b) m = fmaxf(m, parts2[(long)b * 512 + t]);
    hm[t] = m;
    __syncthreads();
    if (t < 256) {
        const float* w = ow + (long)t * 512;
        float s = 0.f;
        for (int d = 0; d < 512; ++d) s += hm[d] * w[d];
        out[t] = s + ob[t];
    }
}

// ---------- fused layer: C = X@W^T (bf16 MFMA) + c ; LN ; relu ; store bf16 ; col-red ----------
// BM=128, BN=512 (full width -> LN block-local), BK=32, 512 threads = 8 waves (2Mx4N).
// Double-buffered LDS (2 x 40KB) + minimum 2-phase pipeline: issue stage(k+1) before
// ds_read+MFMA of tile k; __syncthreads() drain per K-step lands after compute cover.
// XOR-swizzle: 16B slot p of row r holds global k-slot (p ^ (r&3)); source pre-swizzled (G21).
template<int KD, bool STORE, int REDOP>  // REDOP 0=sum, 1=max
__global__ __launch_bounds__(512, 2)
void layer_kernel(const bf16* __restrict__ X, const bf16* __restrict__ W,
                  const float* __restrict__ cvec, const float* __restrict__ gvec,
                  const float* __restrict__ bvec, bf16* __restrict__ Hout,
                  float* __restrict__ red_out) {
    static_assert(KD % 32 == 0, "");
    constexpr int NK = KD / 32;
    // per buffer: Xs[128][32] bf16 = 8192 B, Ws[512][32] bf16 = 32768 B
    __shared__ __align__(128) char smem[2 * 40960];

    const int t = threadIdx.x;
    const int lane = t & 63;
    const int wid = t >> 6;          // 0..7
    const int wm = wid >> 2;         // 0..1  (M half: 64 rows)
    const int wn = wid & 3;          // 0..3  (N quarter: 128 cols)
    const int ln15 = lane & 15;
    const int lg = lane >> 4;        // 0..3
    const long row0 = (long)blockIdx.x * 128;

    f32x4 acc[4][8];
#pragma unroll
    for (int i = 0; i < 4; ++i)
#pragma unroll
        for (int j = 0; j < 8; ++j) acc[i][j] = (f32x4){0.f, 0.f, 0.f, 0.f};

    // ---- staging geometry: thread t stages 16B for row sr, 16B-slot ss ----
    const int sr = t >> 2;           // 0..127
    const int ss = t & 3;            // 0..3
    const int swz_off = ((ss ^ (sr & 3)) * 8);   // element offset within 32-wide k-tile
    long xrow = row0 + sr; if (xrow > NPTS - 1) xrow = NPTS - 1;  // clamp; masked later
    const bf16* xsrc = X + xrow * KD + swz_off;
    const bf16* wsrc0 = W + (long)(0 * 128 + sr) * KD + swz_off;
    const bf16* wsrc1 = W + (long)(1 * 128 + sr) * KD + swz_off;
    const bf16* wsrc2 = W + (long)(2 * 128 + sr) * KD + swz_off;
    const bf16* wsrc3 = W + (long)(3 * 128 + sr) * KD + swz_off;

    // prologue: stage tile 0 into buf 0
    {
        char* Xs = smem;
        char* Ws = smem + 8192;
        async_copy16(xsrc, Xs + t * 16);
        async_copy16(wsrc0, Ws + 0 * 8192 + t * 16);
        async_copy16(wsrc1, Ws + 1 * 8192 + t * 16);
        async_copy16(wsrc2, Ws + 2 * 8192 + t * 16);
        async_copy16(wsrc3, Ws + 3 * 8192 + t * 16);
    }
    __syncthreads();   // drains vmcnt + barrier

    for (int ks = 0; ks < NK; ++ks) {
        // issue next-tile staging first (overlaps with ds_read + MFMA below)
        if (ks + 1 < NK) {
            const int k0 = (ks + 1) * 32;
            char* Xs = smem + ((ks + 1) & 1) * 40960;
            char* Ws = Xs + 8192;
            async_copy16(xsrc + k0, Xs + t * 16);
            async_copy16(wsrc0 + k0, Ws + 0 * 8192 + t * 16);
            async_copy16(wsrc1 + k0, Ws + 1 * 8192 + t * 16);
            async_copy16(wsrc2 + k0, Ws + 2 * 8192 + t * 16);
            async_copy16(wsrc3 + k0, Ws + 3 * 8192 + t * 16);
        }

        const char* Xs = smem + (ks & 1) * 40960;
        const char* Ws = Xs + 8192;
        bf16x8 a[4], b[8];
#pragma unroll
        for (int fm = 0; fm < 4; ++fm) {
            int r = wm * 64 + fm * 16 + ln15;
            a[fm] = *(const bf16x8*)(Xs + r * 64 + ((lg ^ (r & 3)) * 16));
        }
#pragma unroll
        for (int fn = 0; fn < 8; ++fn) {
            int r = wn * 128 + fn * 16 + ln15;
            b[fn] = *(const bf16x8*)(Ws + r * 64 + ((lg ^ (r & 3)) * 16));
        }
#pragma unroll
        for (int fm = 0; fm < 4; ++fm)
#pragma unroll
            for (int fn = 0; fn < 8; ++fn)
                acc[fm][fn] = __builtin_amdgcn_mfma_f32_16x16x32_bf16(a[fm], b[fn], acc[fm][fn], 0, 0, 0);

        __syncthreads();   // drain (covers next-tile loads) + barrier
    }

    // ---------------- epilogue (reuses buf0 region of LDS) ----------------
    float* lnred_s = (float*)smem;            // [128][4]
    float* lnred_q = (float*)(smem + 2048);   // [128][4]
    float* lnmv    = (float*)(smem + 4096);   // [128][2]
    float* csred   = (float*)(smem + 5120);   // [2][512]

    // per-lane column constants (8 cols: wn*128 + fn*16 + ln15)
    const int cbase = wn * 128 + ln15;
    float cv[8], gv[8], bv[8];
#pragma unroll
    for (int fn = 0; fn < 8; ++fn) {
        int col = cbase + fn * 16;
        cv[fn] = cvec[col]; gv[fn] = gvec[col]; bv[fn] = bvec[col];
    }

    // add the broadcast c-vector (fp32-exact common term)
#pragma unroll
    for (int fm = 0; fm < 4; ++fm)
#pragma unroll
        for (int fn = 0; fn < 8; ++fn) acc[fm][fn] += cv[fn];

    // per-row sum / sumsq over this wave's 128 cols (shfl tree within 16-lane group)
    float rs[16], rq[16];
#pragma unroll
    for (int fm = 0; fm < 4; ++fm)
#pragma unroll
        for (int j = 0; j < 4; ++j) {
            float s = 0.f, q = 0.f;
#pragma unroll
            for (int fn = 0; fn < 8; ++fn) {
                float x = acc[fm][fn][j];
                s += x; q += x * x;
            }
            rs[fm * 4 + j] = s; rq[fm * 4 + j] = q;
        }
#pragma unroll
    for (int m = 1; m < 16; m <<= 1)
#pragma unroll
        for (int i = 0; i < 16; ++i) {
            rs[i] += __shfl_xor(rs[i], m);
            rq[i] += __shfl_xor(rq[i], m);
        }
    if (ln15 == 0) {
#pragma unroll
        for (int fm = 0; fm < 4; ++fm)
#pragma unroll
            for (int j = 0; j < 4; ++j) {
                int row = wm * 64 + fm * 16 + lg * 4 + j;
                lnred_s[row * 4 + wn] = rs[fm * 4 + j];
                lnred_q[row * 4 + wn] = rq[fm * 4 + j];
            }
    }
    __syncthreads();
    if (t < 128) {
        float s = lnred_s[t * 4] + lnred_s[t * 4 + 1] + lnred_s[t * 4 + 2] + lnred_s[t * 4 + 3];
        float q = lnred_q[t * 4] + lnred_q[t * 4 + 1] + lnred_q[t * 4 + 2] + lnred_q[t * 4 + 3];
        float mu = s * (1.0f / 512.0f);
        float var = q * (1.0f / 512.0f) - mu * mu;
        lnmv[t * 2] = mu;
        lnmv[t * 2 + 1] = rsqrtf(var + EPSV);
    }
    __syncthreads();

    // normalize + relu + (store bf16) ; invalid rows forced to 0 so col-reductions are masked
#pragma unroll
    for (int fm = 0; fm < 4; ++fm)
#pragma unroll
        for (int j = 0; j < 4; ++j) {
            int rloc = wm * 64 + fm * 16 + lg * 4 + j;
            long rglob = row0 + rloc;
            bool ok = rglob < NPTS;
            float mu = lnmv[rloc * 2], rstd = lnmv[rloc * 2 + 1];
#pragma unroll
            for (int fn = 0; fn < 8; ++fn) {
                float y = fmaxf((acc[fm][fn][j] - mu) * rstd * gv[fn] + bv[fn], 0.0f);
                acc[fm][fn][j] = ok ? y : 0.0f;
            }
            if (STORE && ok) {
#pragma unroll
                for (int fn = 0; fn < 8; ++fn)
                    Hout[rglob * DHID + cbase + fn * 16] = (bf16)acc[fm][fn][j];
            }
        }

    // column partials over the block's 128 rows (sum or max)
    float cp[8];
#pragma unroll
    for (int fn = 0; fn < 8; ++fn) {
        float p = 0.f;
#pragma unroll
        for (int fm = 0; fm < 4; ++fm)
#pragma unroll
            for (int j = 0; j < 4; ++j) {
                float v = acc[fm][fn][j];
                p = (REDOP == 0) ? (p + v) : fmaxf(p, v);
            }
        cp[fn] = p;
    }
#pragma unroll
    for (int m = 16; m < 64; m <<= 1)
#pragma unroll
        for (int fn = 0; fn < 8; ++fn) {
            float o = __shfl_xor(cp[fn], m);
            cp[fn] = (REDOP == 0) ? (cp[fn] + o) : fmaxf(cp[fn], o);
        }
    if (lg == 0) {
#pragma unroll
        for (int fn = 0; fn < 8; ++fn)
            csred[wm * 512 + wn * 128 + fn * 16 + ln15] = cp[fn];
    }
    __syncthreads();
    {
        float a0 = csred[t], a1 = csred[512 + t];
        red_out[(long)blockIdx.x * 512 + t] = (REDOP == 0) ? (a0 + a1) : fmaxf(a0, a1);
    }
}

extern "C" void kernel_launch(void* const* d_in, const int* in_sizes, int n_in,
                              void* d_out, int out_size, void* d_ws, size_t ws_size,
                              hipStream_t stream) {
    const float* in_set = (const float*)d_in[0];
    const float* A0 = (const float*)d_in[1];
    const float* B0 = (const float*)d_in[2];
    const float* A1 = (const float*)d_in[3];
    const float* B1 = (const float*)d_in[4];
    const float* A2 = (const float*)d_in[5];
    const float* B2 = (const float*)d_in[6];
    const float* ga = (const float*)d_in[7];
    const float* be = (const float*)d_in[8];
    const float* ow = (const float*)d_in[9];
    const float* ob = (const float*)d_in[10];
    float* outp = (float*)d_out;
    char* ws = (char*)d_ws;

    bf16* in_bf = (bf16*)(ws + OFF_INBF);
    bf16* W0 = (bf16*)(ws + OFF_W0);
    bf16* W1 = (bf16*)(ws + OFF_W1);
    bf16* W2 = (bf16*)(ws + OFF_W2);
    float* c0 = (float*)(ws + OFF_C0);
    float* c1 = (float*)(ws + OFF_C1);
    float* c2 = (float*)(ws + OFF_C2);
    float* parts = (float*)(ws + OFF_PARTS);
    float* parts2 = (float*)(ws + OFF_PARTS2);
    bf16* h1 = (bf16*)(ws + OFF_H1);
    bf16* h2 = (bf16*)(ws + OFF_H2);

    const int nblk = (NPTS + 127) / 128;  // 782

    cvt_bf16_kernel<<<2048, 256, 0, stream>>>(in_set, in_bf, (long)NPTS * 128);
    wdiff_kernel<<<64, 256, 0, stream>>>(A0, B0, W0, 512L * 128);
    wdiff_kernel<<<256, 256, 0, stream>>>(A1, B1, W1, 512L * 512);
    wdiff_kernel<<<256, 256, 0, stream>>>(A2, B2, W2, 512L * 512);

    // c0 = colsum(in_set) @ B0^T   (all fp32 — the numerically critical path)
    colsum_in_kernel<<<512, 256, 0, stream>>>(in_set, parts);
    reduce_c_kernel<<<1, 512, 0, stream>>>(parts, 512, 128, B0, c0);

    layer_kernel<128, true, 0><<<nblk, 512, 0, stream>>>(in_bf, W0, c0, ga, be, h1, parts);
    part_reduce_kernel<<<64, 512, 0, stream>>>(parts, nblk, 0, parts2);
    reduce_c_kernel<<<1, 512, 0, stream>>>(parts2, 64, 512, B1, c1);

    layer_kernel<512, true, 0><<<nblk, 512, 0, stream>>>(h1, W1, c1, ga, be, h2, parts);
    part_reduce_kernel<<<64, 512, 0, stream>>>(parts, nblk, 0, parts2);
    reduce_c_kernel<<<1, 512, 0, stream>>>(parts2, 64, 512, B2, c2);

    // layer 2: no h3 store; fused column-max partials
    layer_kernel<512, false, 1><<<nblk, 512, 0, stream>>>(h2, W2, c2, ga, be, nullptr, parts);
    part_reduce_kernel<<<64, 512, 0, stream>>>(parts, nblk, 1, parts2);
    final_kernel<<<1, 512, 0, stream>>>(parts2, 64, ow, ob, outp);
}

// Round 3
// 353.336 us; speedup vs baseline: 1.7603x; 1.7313x over previous
//
#include <hip/hip_runtime.h>
#include <hip/hip_bf16.h>

#define NPTS 100000
#define DHID 512
#define EPSV 1e-5f

typedef __bf16 bf16;
typedef __attribute__((ext_vector_type(8))) __bf16 bf16x8;
typedef __attribute__((ext_vector_type(4))) __bf16 bf16x4;
typedef __attribute__((ext_vector_type(4))) float f32x4;

// ---- workspace layout (bytes) ----
#define OFF_INBF   0UL            // 100000*128*2
#define OFF_W0     25600000UL     // 512*128*2
#define OFF_W1     25731072UL     // 512*512*2
#define OFF_W2     26255360UL     // 512*512*2
#define OFF_C0     26779648UL     // 512*4
#define OFF_C1     26781696UL
#define OFF_C2     26783744UL
#define OFF_PARTS  26785792UL     // (up to 1563)*512*4
#define OFF_PARTS2 29986816UL     // 64*512*4
#define OFF_PARTS3 30117888UL     // 8*512*4
#define OFF_H1     30134272UL     // 100000*512*2
#define OFF_H2     132534272UL    // 100000*512*2

typedef const __attribute__((address_space(1))) unsigned int* gp_t;
typedef __attribute__((address_space(3))) unsigned int* lp_t;

__device__ __forceinline__ void async_copy16(const void* g, void* l) {
    __builtin_amdgcn_global_load_lds((gp_t)g, (lp_t)l, 16, 0, 0);
}

// ---------- prep: fp32 -> bf16 ----------
__global__ __launch_bounds__(256) void cvt_bf16_kernel(const float* __restrict__ in,
                                                       bf16* __restrict__ out, long n) {
    long stride = (long)gridDim.x * blockDim.x * 4;
    for (long base = ((long)blockIdx.x * blockDim.x + threadIdx.x) * 4; base < n; base += stride) {
        float4 v = *(const float4*)(in + base);
        bf16x4 o = { (bf16)v.x, (bf16)v.y, (bf16)v.z, (bf16)v.w };
        *(bf16x4*)(out + base) = o;
    }
}

// ---------- prep: W = bf16(A - B) ----------
__global__ __launch_bounds__(256) void wdiff_kernel(const float* __restrict__ A,
                                                    const float* __restrict__ B,
                                                    bf16* __restrict__ W, long n) {
    long stride = (long)gridDim.x * blockDim.x * 4;
    for (long base = ((long)blockIdx.x * blockDim.x + threadIdx.x) * 4; base < n; base += stride) {
        float4 a = *(const float4*)(A + base);
        float4 b = *(const float4*)(B + base);
        bf16x4 o = { (bf16)(a.x - b.x), (bf16)(a.y - b.y), (bf16)(a.z - b.z), (bf16)(a.w - b.w) };
        *(bf16x4*)(W + base) = o;
    }
}

// ---------- colsum of in_set (fp32, deterministic 2-stage) ----------
__global__ __launch_bounds__(256) void colsum_in_kernel(const float* __restrict__ in,
                                                        float* __restrict__ parts) {
    __shared__ float sh[256];
    int t = threadIdx.x, blk = blockIdx.x;
    int c = t & 127, half = t >> 7;
    long rbeg = (long)blk * 196 + half;
    long rend = (long)(blk + 1) * 196; if (rend > NPTS) rend = NPTS;
    float s = 0.f;
    for (long r = rbeg; r < rend; r += 2) s += in[r * 128 + c];
    sh[t] = s;
    __syncthreads();
    if (t < 128) parts[blk * 128 + t] = sh[t] + sh[t + 128];
}

// ---------- generic partial reduce: parts[nparts][width] -> out[grid][width] ----------
__global__ void part_reduceW_kernel(const float* __restrict__ parts, int nparts, int width,
                                    int op, float* __restrict__ out) {
    int g = blockIdx.x, t = threadIdx.x;
    int chunk = (nparts + gridDim.x - 1) / gridDim.x;
    int b0 = g * chunk, b1 = b0 + chunk; if (b1 > nparts) b1 = nparts;
    float s = 0.f;  // identity 0 valid for max too: values are post-relu >= 0
    for (int b = b0; b < b1; ++b) {
        float v = parts[(long)b * width + t];
        s = (op == 0) ? (s + v) : fmaxf(s, v);
    }
    out[(long)g * width + t] = s;
}

// ---------- fold 8 partial rows + GEMV: out[j] = (fold_g p3[g][:]) . Bm[j][:] + bias ----------
// one wave per output column; p3 is [8][dsum]
__global__ __launch_bounds__(64) void gemv_fold_kernel(const float* __restrict__ p3, int dsum,
                                                       const float* __restrict__ Bm,
                                                       const float* __restrict__ bias, int op,
                                                       float* __restrict__ out) {
    int j = blockIdx.x, t = threadIdx.x;
    float acc = 0.f;
    for (int d = t; d < dsum; d += 64) {
        float s = 0.f;
#pragma unroll
        for (int g = 0; g < 8; ++g) {
            float v = p3[(long)g * dsum + d];
            s = (op == 0) ? (s + v) : fmaxf(s, v);
        }
        acc += s * Bm[(long)j * dsum + d];
    }
#pragma unroll
    for (int m = 32; m >= 1; m >>= 1) acc += __shfl_down(acc, m);
    if (t == 0) out[j] = acc + (bias ? bias[j] : 0.0f);
}

// ---------- fused layer: C = X@W^T (bf16 MFMA) + c ; LN ; relu ; store bf16 ; col-red ----------
// BM=128, BN=512 (full width -> LN block-local), BK=32, 512 threads = 8 waves (2Mx4N).
// Double-buffered LDS (2 x 40KB) + counted-vmcnt pipeline: raw s_barrier, vmcnt(5) keeps the
// next tile's 5 global_load_lds in flight across barriers (T4); drain to 0 only at the end.
// Swizzle: 16B slot p of row r holds global k-slot p ^ ((r>>1)&3) -> each 8-lane ds_read_b128
// phase covers 8 distinct (bank-half, quad) positions => conflict-free.
template<int KD, bool STORE, int REDOP>  // REDOP 0=sum, 1=max
__global__ __launch_bounds__(512, 2)
void layer_kernel(const bf16* __restrict__ X, const bf16* __restrict__ W,
                  const float* __restrict__ cvec, const float* __restrict__ gvec,
                  const float* __restrict__ bvec, bf16* __restrict__ Hout,
                  float* __restrict__ red_out) {
    static_assert(KD % 32 == 0, "");
    constexpr int NK = KD / 32;
    // per buffer: Xs[128][32] bf16 = 8192 B, Ws[512][32] bf16 = 32768 B
    __shared__ __align__(128) char smem[2 * 40960];

    const int t = threadIdx.x;
    const int lane = t & 63;
    const int wid = t >> 6;          // 0..7
    const int wm = wid >> 2;         // 0..1  (M half: 64 rows)
    const int wn = wid & 3;          // 0..3  (N quarter: 128 cols)
    const int ln15 = lane & 15;
    const int lg = lane >> 4;        // 0..3
    const long row0 = (long)blockIdx.x * 128;

    f32x4 acc[4][8];
#pragma unroll
    for (int i = 0; i < 4; ++i)
#pragma unroll
        for (int j = 0; j < 8; ++j) acc[i][j] = (f32x4){0.f, 0.f, 0.f, 0.f};

    // ---- staging geometry: thread t stages 16B for row sr, 16B-slot ss ----
    const int sr = t >> 2;           // 0..127
    const int ss = t & 3;            // 0..3
    const int swz_off = ((ss ^ ((sr >> 1) & 3)) * 8);   // element offset within 32-wide k-tile
    long xrow = row0 + sr; if (xrow > NPTS - 1) xrow = NPTS - 1;  // clamp; masked later
    const bf16* xsrc = X + xrow * KD + swz_off;
    const bf16* wsrc0 = W + (long)(0 * 128 + sr) * KD + swz_off;
    const bf16* wsrc1 = W + (long)(1 * 128 + sr) * KD + swz_off;
    const bf16* wsrc2 = W + (long)(2 * 128 + sr) * KD + swz_off;
    const bf16* wsrc3 = W + (long)(3 * 128 + sr) * KD + swz_off;

    auto stage = [&](int ks) {
        const int k0 = ks * 32;
        char* Xs = smem + (ks & 1) * 40960;
        char* Ws = Xs + 8192;
        async_copy16(xsrc + k0, Xs + t * 16);
        async_copy16(wsrc0 + k0, Ws + 0 * 8192 + t * 16);
        async_copy16(wsrc1 + k0, Ws + 1 * 8192 + t * 16);
        async_copy16(wsrc2 + k0, Ws + 2 * 8192 + t * 16);
        async_copy16(wsrc3 + k0, Ws + 3 * 8192 + t * 16);
    };

    // prologue: 2 tiles in flight (10 outstanding vmem)
    stage(0);
    stage(1);

#pragma unroll
    for (int ks = 0; ks < NK; ++ks) {
        // wait for tile ks only (tile ks+1's 5 loads stay in flight)
        if (ks < NK - 1) asm volatile("s_waitcnt vmcnt(5)" ::: "memory");
        else             asm volatile("s_waitcnt vmcnt(0)" ::: "memory");
        __builtin_amdgcn_s_barrier();

        const char* Xs = smem + (ks & 1) * 40960;
        const char* Ws = Xs + 8192;
        bf16x8 a[4], b[8];
#pragma unroll
        for (int fm = 0; fm < 4; ++fm) {
            int r = wm * 64 + fm * 16 + ln15;
            a[fm] = *(const bf16x8*)(Xs + r * 64 + ((lg ^ ((r >> 1) & 3)) * 16));
        }
#pragma unroll
        for (int fn = 0; fn < 8; ++fn) {
            int r = wn * 128 + fn * 16 + ln15;
            b[fn] = *(const bf16x8*)(Ws + r * 64 + ((lg ^ ((r >> 1) & 3)) * 16));
        }
#pragma unroll
        for (int fm = 0; fm < 4; ++fm)
#pragma unroll
            for (int fn = 0; fn < 8; ++fn)
                acc[fm][fn] = __builtin_amdgcn_mfma_f32_16x16x32_bf16(a[fm], b[fn], acc[fm][fn], 0, 0, 0);

        // all this wave's LDS reads complete before signaling buffer-free
        asm volatile("s_waitcnt lgkmcnt(0)" ::: "memory");
        __builtin_amdgcn_sched_barrier(0);
        __builtin_amdgcn_s_barrier();
        __builtin_amdgcn_sched_barrier(0);
        if (ks + 2 < NK) stage(ks + 2);
    }

    // ---------------- epilogue (reuses buf0 region of LDS) ----------------
    float* lnred_s = (float*)smem;            // [128][4]
    float* lnred_q = (float*)(smem + 2048);   // [128][4]
    float* lnmv    = (float*)(smem + 4096);   // [128][2]
    float* csred   = (float*)(smem + 5120);   // [2][512]

    // per-lane column constants (8 cols: wn*128 + fn*16 + ln15)
    const int cbase = wn * 128 + ln15;
    float cv[8], gv[8], bv[8];
#pragma unroll
    for (int fn = 0; fn < 8; ++fn) {
        int col = cbase + fn * 16;
        cv[fn] = cvec[col]; gv[fn] = gvec[col]; bv[fn] = bvec[col];
    }

    // add the broadcast c-vector (fp32-exact common term)
#pragma unroll
    for (int fm = 0; fm < 4; ++fm)
#pragma unroll
        for (int fn = 0; fn < 8; ++fn) acc[fm][fn] += cv[fn];

    // per-row sum / sumsq over this wave's 128 cols (shfl tree within 16-lane group)
    float rs[16], rq[16];
#pragma unroll
    for (int fm = 0; fm < 4; ++fm)
#pragma unroll
        for (int j = 0; j < 4; ++j) {
            float s = 0.f, q = 0.f;
#pragma unroll
            for (int fn = 0; fn < 8; ++fn) {
                float x = acc[fm][fn][j];
                s += x; q += x * x;
            }
            rs[fm * 4 + j] = s; rq[fm * 4 + j] = q;
        }
#pragma unroll
    for (int m = 1; m < 16; m <<= 1)
#pragma unroll
        for (int i = 0; i < 16; ++i) {
            rs[i] += __shfl_xor(rs[i], m);
            rq[i] += __shfl_xor(rq[i], m);
        }
    if (ln15 == 0) {
#pragma unroll
        for (int fm = 0; fm < 4; ++fm)
#pragma unroll
            for (int j = 0; j < 4; ++j) {
                int row = wm * 64 + fm * 16 + lg * 4 + j;
                lnred_s[row * 4 + wn] = rs[fm * 4 + j];
                lnred_q[row * 4 + wn] = rq[fm * 4 + j];
            }
    }
    __syncthreads();
    if (t < 128) {
        float s = lnred_s[t * 4] + lnred_s[t * 4 + 1] + lnred_s[t * 4 + 2] + lnred_s[t * 4 + 3];
        float q = lnred_q[t * 4] + lnred_q[t * 4 + 1] + lnred_q[t * 4 + 2] + lnred_q[t * 4 + 3];
        float mu = s * (1.0f / 512.0f);
        float var = q * (1.0f / 512.0f) - mu * mu;
        lnmv[t * 2] = mu;
        lnmv[t * 2 + 1] = rsqrtf(var + EPSV);
    }
    __syncthreads();

    // normalize + relu + (store bf16) ; invalid rows forced to 0 so col-reductions are masked
#pragma unroll
    for (int fm = 0; fm < 4; ++fm)
#pragma unroll
        for (int j = 0; j < 4; ++j) {
            int rloc = wm * 64 + fm * 16 + lg * 4 + j;
            long rglob = row0 + rloc;
            bool ok = rglob < NPTS;
            float mu = lnmv[rloc * 2], rstd = lnmv[rloc * 2 + 1];
#pragma unroll
            for (int fn = 0; fn < 8; ++fn) {
                float y = fmaxf((acc[fm][fn][j] - mu) * rstd * gv[fn] + bv[fn], 0.0f);
                acc[fm][fn][j] = ok ? y : 0.0f;
            }
            if (STORE && ok) {
#pragma unroll
                for (int fn = 0; fn < 8; ++fn)
                    Hout[rglob * DHID + cbase + fn * 16] = (bf16)acc[fm][fn][j];
            }
        }

    // column partials over the block's 128 rows (sum or max)
    float cp[8];
#pragma unroll
    for (int fn = 0; fn < 8; ++fn) {
        float p = 0.f;
#pragma unroll
        for (int fm = 0; fm < 4; ++fm)
#pragma unroll
            for (int j = 0; j < 4; ++j) {
                float v = acc[fm][fn][j];
                p = (REDOP == 0) ? (p + v) : fmaxf(p, v);
            }
        cp[fn] = p;
    }
#pragma unroll
    for (int m = 16; m < 64; m <<= 1)
#pragma unroll
        for (int fn = 0; fn < 8; ++fn) {
            float o = __shfl_xor(cp[fn], m);
            cp[fn] = (REDOP == 0) ? (cp[fn] + o) : fmaxf(cp[fn], o);
        }
    if (lg == 0) {
#pragma unroll
        for (int fn = 0; fn < 8; ++fn)
            csred[wm * 512 + wn * 128 + fn * 16 + ln15] = cp[fn];
    }
    __syncthreads();
    {
        float a0 = csred[t], a1 = csred[512 + t];
        red_out[(long)blockIdx.x * 512 + t] = (REDOP == 0) ? (a0 + a1) : fmaxf(a0, a1);
    }
}

extern "C" void kernel_launch(void* const* d_in, const int* in_sizes, int n_in,
                              void* d_out, int out_size, void* d_ws, size_t ws_size,
                              hipStream_t stream) {
    const float* in_set = (const float*)d_in[0];
    const float* A0 = (const float*)d_in[1];
    const float* B0 = (const float*)d_in[2];
    const float* A1 = (const float*)d_in[3];
    const float* B1 = (const float*)d_in[4];
    const float* A2 = (const float*)d_in[5];
    const float* B2 = (const float*)d_in[6];
    const float* ga = (const float*)d_in[7];
    const float* be = (const float*)d_in[8];
    const float* ow = (const float*)d_in[9];
    const float* ob = (const float*)d_in[10];
    float* outp = (float*)d_out;
    char* ws = (char*)d_ws;

    bf16* in_bf = (bf16*)(ws + OFF_INBF);
    bf16* W0 = (bf16*)(ws + OFF_W0);
    bf16* W1 = (bf16*)(ws + OFF_W1);
    bf16* W2 = (bf16*)(ws + OFF_W2);
    float* c0 = (float*)(ws + OFF_C0);
    float* c1 = (float*)(ws + OFF_C1);
    float* c2 = (float*)(ws + OFF_C2);
    float* parts = (float*)(ws + OFF_PARTS);
    float* parts2 = (float*)(ws + OFF_PARTS2);
    float* parts3 = (float*)(ws + OFF_PARTS3);
    bf16* h1 = (bf16*)(ws + OFF_H1);
    bf16* h2 = (bf16*)(ws + OFF_H2);

    const int nblk = (NPTS + 127) / 128;  // 782

    cvt_bf16_kernel<<<2048, 256, 0, stream>>>(in_set, in_bf, (long)NPTS * 128);
    wdiff_kernel<<<64, 256, 0, stream>>>(A0, B0, W0, 512L * 128);
    wdiff_kernel<<<256, 256, 0, stream>>>(A1, B1, W1, 512L * 512);
    wdiff_kernel<<<256, 256, 0, stream>>>(A2, B2, W2, 512L * 512);

    // c0 = colsum(in_set) @ B0^T  (all fp32 — the numerically critical path), wide+shallow
    colsum_in_kernel<<<512, 256, 0, stream>>>(in_set, parts);                       // [512][128]
    part_reduceW_kernel<<<64, 128, 0, stream>>>(parts, 512, 128, 0, parts2);        // [64][128]
    part_reduceW_kernel<<<8, 128, 0, stream>>>(parts2, 64, 128, 0, parts3);         // [8][128]
    gemv_fold_kernel<<<512, 64, 0, stream>>>(parts3, 128, B0, nullptr, 0, c0);

    layer_kernel<128, true, 0><<<nblk, 512, 0, stream>>>(in_bf, W0, c0, ga, be, h1, parts);
    part_reduceW_kernel<<<64, 512, 0, stream>>>(parts, nblk, 512, 0, parts2);
    part_reduceW_kernel<<<8, 512, 0, stream>>>(parts2, 64, 512, 0, parts3);
    gemv_fold_kernel<<<512, 64, 0, stream>>>(parts3, 512, B1, nullptr, 0, c1);

    layer_kernel<512, true, 0><<<nblk, 512, 0, stream>>>(h1, W1, c1, ga, be, h2, parts);
    part_reduceW_kernel<<<64, 512, 0, stream>>>(parts, nblk, 512, 0, parts2);
    part_reduceW_kernel<<<8, 512, 0, stream>>>(parts2, 64, 512, 0, parts3);
    gemv_fold_kernel<<<512, 64, 0, stream>>>(parts3, 512, B2, nullptr, 0, c2);

    // layer 2: no h3 store; fused column-max partials; final = (max-fold) @ ow^T + ob
    layer_kernel<512, false, 1><<<nblk, 512, 0, stream>>>(h2, W2, c2, ga, be, nullptr, parts);
    part_reduceW_kernel<<<64, 512, 0, stream>>>(parts, nblk, 512, 1, parts2);
    part_reduceW_kernel<<<8, 512, 0, stream>>>(parts2, 64, 512, 1, parts3);
    gemv_fold_kernel<<<256, 64, 0, stream>>>(parts3, 512, ow, ob, 1, outp);
}